// Round 1
// baseline (286.022 us; speedup 1.0000x reference)
//
#include <hip/hip_runtime.h>

// Problem constants
#define NROWS   200000
#define DSPA    3
#define FIN     128
#define FMID    512
#define FOUT    128
#define TILE    32           // rows (n) per block
#define NBLOCKS (NROWS / TILE)   // 6250, exact

typedef __attribute__((ext_vector_type(4))) float f32x4;
typedef __attribute__((ext_vector_type(8))) short bf16x8;

// fp32 -> bf16 round-to-nearest-even (bit trick; inputs are finite/normal)
__device__ __forceinline__ unsigned short f2bf(float f) {
  unsigned b = __float_as_uint(f);
  b += 0x7fffu + ((b >> 16) & 1u);
  return (unsigned short)(b >> 16);
}

__device__ __forceinline__ f32x4 mfma16(bf16x8 a, bf16x8 b, f32x4 c) {
  return __builtin_amdgcn_mfma_f32_16x16x32_bf16(a, b, c, 0, 0, 0);
}

// tanh via exp2-based fast exp; exact at saturation (e=inf -> 1, e=0 -> -1)
__device__ __forceinline__ float fast_tanh(float x) {
  float e = __expf(2.0f * x);
  return 1.0f - __fdividef(2.0f, e + 1.0f);
}

// ---------------------------------------------------------------------------
// Weight prep: convert W[K][Nout] (fp32, row-major) to bf16 in MFMA-B
// fragment order. For fragment block (kt,nt) stored at index (kt*NT + nt):
//   lane l, elem i  <-  W[kt*32 + 8*(l>>4) + i][nt*16 + (l&15)]
// so the main kernel loads a B-fragment as one coalesced 16B load per lane.
// Fragment blocks: Wp: 4*8=32, W1: 4*32=128, W2: 16*8=128  -> 288 total.
// ---------------------------------------------------------------------------
__global__ void prep_weights(const float* __restrict__ Wp,
                             const float* __restrict__ W1,
                             const float* __restrict__ W2,
                             unsigned short* __restrict__ wpf,
                             unsigned short* __restrict__ w1f,
                             unsigned short* __restrict__ w2f) {
  int t = blockIdx.x * 256 + threadIdx.x;   // 72*256 = 18432 = 288*64
  int q = t >> 6, l = t & 63;
  const float* W; unsigned short* dst; int NT, Nout, qb;
  if (q < 32)       { W = Wp; dst = wpf; NT = 8;  Nout = 128; qb = q; }
  else if (q < 160) { W = W1; dst = w1f; NT = 32; Nout = 512; qb = q - 32; }
  else              { W = W2; dst = w2f; NT = 8;  Nout = 128; qb = q - 160; }
  int kt = qb / NT, nt = qb % NT;
  int row0 = kt * 32 + 8 * (l >> 4);
  int col  = nt * 16 + (l & 15);
  unsigned short v[8];
#pragma unroll
  for (int i = 0; i < 8; ++i) v[i] = f2bf(W[(row0 + i) * Nout + col]);
  uint4 pack;
  pack.x = (unsigned)v[0] | ((unsigned)v[1] << 16);
  pack.y = (unsigned)v[2] | ((unsigned)v[3] << 16);
  pack.z = (unsigned)v[4] | ((unsigned)v[5] << 16);
  pack.w = (unsigned)v[6] | ((unsigned)v[7] << 16);
  *(uint4*)(dst + (size_t)(qb * 64 + l) * 8) = pack;
}

// ---------------------------------------------------------------------------
// Fused main kernel. Per block: 32 rows (n), 256 threads = 4 waves.
// LDS plan (58880 B total -> 2 blocks/CU):
//   [0,     33280): union { x_lds bf16 [96][136]  (rows' = 3n+d, pitch 136)
//                           h1_lds bf16 [32][520] }   (x dead after GEMM1)
//   [33280, 41984): c_lds bf16 [32][136]
//   [41984, 58880): h2_lds f32 [32][132]
// GEMM1 (linear_x) accumulators stay in VGPRs across GEMM2/3.
// MFMA 16x16x32 layouts (measured, m89/m91):
//   A: lane l holds A[l&15][8*(l>>4)+i], i=0..7   (16B contiguous in k)
//   B: lane l holds B[8*(l>>4)+i][l&15]           (prepped fragment order)
//   D: lane l reg r holds D[4*(l>>4)+r][l&15]
// ---------------------------------------------------------------------------
__global__ __launch_bounds__(256, 2) void fused_kernel(
    const float* __restrict__ x,
    const float* __restrict__ b1,
    const float* __restrict__ b2,
    const unsigned short* __restrict__ wpf,
    const unsigned short* __restrict__ w1f,
    const unsigned short* __restrict__ w2f,
    float* __restrict__ out) {
  __shared__ __align__(16) char smem[58880];
  unsigned short* xh1 = (unsigned short*)smem;            // x[96][136] / h1[32][520]
  unsigned short* c_l = (unsigned short*)(smem + 33280);  // c[32][136]
  float*          h2_l = (float*)(smem + 41984);          // h2[32][132]

  const int t = threadIdx.x;
  const int l = t & 63;
  const int w = t >> 6;
  const long n0 = (long)blockIdx.x * TILE;

  // ---- P0: stage x -> bf16 LDS; c = sum_d x^2 computed in fp32 from
  //      UN-rounded x (precision-critical), then rounded once to bf16.
#pragma unroll
  for (int k = 0; k < 4; ++k) {
    int p = t + k * 256;            // 0..1023
    int r = p >> 5;                 // row n-local 0..31
    int f = (p & 31) * 4;           // feature 0..124
    const float* xp = x + (n0 + r) * 384 + f;
    float4 v0 = *(const float4*)(xp);
    float4 v1 = *(const float4*)(xp + 128);
    float4 v2 = *(const float4*)(xp + 256);
    float c0 = v0.x * v0.x + v1.x * v1.x + v2.x * v2.x;
    float c1 = v0.y * v0.y + v1.y * v1.y + v2.y * v2.y;
    float c2 = v0.z * v0.z + v1.z * v1.z + v2.z * v2.z;
    float c3 = v0.w * v0.w + v1.w * v1.w + v2.w * v2.w;
    ushort4 s0 = { f2bf(v0.x), f2bf(v0.y), f2bf(v0.z), f2bf(v0.w) };
    ushort4 s1 = { f2bf(v1.x), f2bf(v1.y), f2bf(v1.z), f2bf(v1.w) };
    ushort4 s2 = { f2bf(v2.x), f2bf(v2.y), f2bf(v2.z), f2bf(v2.w) };
    ushort4 sc = { f2bf(c0),   f2bf(c1),   f2bf(c2),   f2bf(c3)   };
    *(ushort4*)(xh1 + (3 * r + 0) * 136 + f) = s0;
    *(ushort4*)(xh1 + (3 * r + 1) * 136 + f) = s1;
    *(ushort4*)(xh1 + (3 * r + 2) * 136 + f) = s2;
    *(ushort4*)(c_l + r * 136 + f) = sc;
  }
  __syncthreads();

  // ---- GEMM1: linear[r'=3n+d][g] = sum_f x[r'][f] * Wp[f][g]
  // 96 rows' = 6 mtiles; 128 cols = 8 ntiles; wave w owns ntiles {2w, 2w+1}.
  // Accumulators held in registers until the final epilogue.
  f32x4 acc1[6][2] = {};
#pragma unroll
  for (int kt = 0; kt < 4; ++kt) {
    bf16x8 a[6];
#pragma unroll
    for (int mt = 0; mt < 6; ++mt) {
      int row = mt * 16 + (l & 15);
      a[mt] = *(const bf16x8*)(xh1 + row * 136 + kt * 32 + 8 * (l >> 4));
    }
#pragma unroll
    for (int jj = 0; jj < 2; ++jj) {
      int nt = 2 * w + jj;
      bf16x8 b = *(const bf16x8*)(wpf + (size_t)((kt * 8 + nt) * 64 + l) * 8);
#pragma unroll
      for (int mt = 0; mt < 6; ++mt)
        acc1[mt][jj] = mfma16(a[mt], b, acc1[mt][jj]);
    }
  }
  __syncthreads();   // x_lds reads complete; region reusable for h1

  // ---- GEMM2: h1 = tanh(c @ W1 + b1).  32x512 out: wave w -> mtile (w>>1),
  // ntiles (w&1)*16 .. +16.
  const int mt2 = w >> 1;
  const int nbase = (w & 1) * 16;
  {
    f32x4 acc2[16] = {};
#pragma unroll
    for (int kt = 0; kt < 4; ++kt) {
      int rowa = mt2 * 16 + (l & 15);
      bf16x8 a = *(const bf16x8*)(c_l + rowa * 136 + kt * 32 + 8 * (l >> 4));
#pragma unroll
      for (int j = 0; j < 16; ++j) {
        int nt = nbase + j;
        bf16x8 b = *(const bf16x8*)(w1f + (size_t)((kt * 32 + nt) * 64 + l) * 8);
        acc2[j] = mfma16(a, b, acc2[j]);
      }
    }
    // epilogue: bias + tanh -> h1_lds (overwrites dead x region)
#pragma unroll
    for (int j = 0; j < 16; ++j) {
      int col = (nbase + j) * 16 + (l & 15);
      float b1v = b1[col];
      int rowb = mt2 * 16 + 4 * (l >> 4);
#pragma unroll
      for (int reg = 0; reg < 4; ++reg) {
        float h = acc2[j][reg] + b1v;
        xh1[(rowb + reg) * 520 + col] = f2bf(fast_tanh(h));
      }
    }
  }
  __syncthreads();

  // ---- GEMM3: h2 = h1 @ W2 + b2.  32x128 out: wave w -> mtile (w>>1),
  // ntiles (w&1)*4 .. +4.  K = 512 -> 16 k-tiles.
  {
    const int nb3 = (w & 1) * 4;
    f32x4 acc3[4] = {};
#pragma unroll
    for (int kt = 0; kt < 16; ++kt) {
      int rowa = mt2 * 16 + (l & 15);
      bf16x8 a = *(const bf16x8*)(xh1 + rowa * 520 + kt * 32 + 8 * (l >> 4));
#pragma unroll
      for (int j = 0; j < 4; ++j) {
        bf16x8 b = *(const bf16x8*)(w2f + (size_t)((kt * 8 + nb3 + j) * 64 + l) * 8);
        acc3[j] = mfma16(a, b, acc3[j]);
      }
    }
#pragma unroll
    for (int j = 0; j < 4; ++j) {
      int col = (nb3 + j) * 16 + (l & 15);
      float b2v = b2[col];
      int rowb = mt2 * 16 + 4 * (l >> 4);
#pragma unroll
      for (int reg = 0; reg < 4; ++reg)
        h2_l[(rowb + reg) * 132 + col] = acc3[j][reg] + b2v;
    }
  }
  __syncthreads();

  // ---- Final epilogue: out[n,d,g] = linear_x[r'][g] * h2[n][g],  r' = 3n+d
#pragma unroll
  for (int mt = 0; mt < 6; ++mt) {
    int rpb = mt * 16 + 4 * (l >> 4);
#pragma unroll
    for (int jj = 0; jj < 2; ++jj) {
      int g = (2 * w + jj) * 16 + (l & 15);
#pragma unroll
      for (int reg = 0; reg < 4; ++reg) {
        int rp = rpb + reg;
        int n = rp / 3;   // compiler emits magic-mul
        float val = acc1[mt][jj][reg] * h2_l[n * 132 + g];
        out[n0 * 384 + (long)rp * 128 + g] = val;
      }
    }
  }
}

extern "C" void kernel_launch(void* const* d_in, const int* in_sizes, int n_in,
                              void* d_out, int out_size, void* d_ws, size_t ws_size,
                              hipStream_t stream) {
  const float* x  = (const float*)d_in[0];
  const float* Wp = (const float*)d_in[1];
  const float* W1 = (const float*)d_in[2];
  const float* b1 = (const float*)d_in[3];
  const float* W2 = (const float*)d_in[4];
  const float* b2 = (const float*)d_in[5];
  float* out = (float*)d_out;

  // ws layout: W1f [128KB] | W2f [128KB] | Wpf [32KB]
  if (ws_size < 294912) return;  // should not happen; loud failure if it does
  unsigned short* w1f = (unsigned short*)d_ws;
  unsigned short* w2f = (unsigned short*)((char*)d_ws + 131072);
  unsigned short* wpf = (unsigned short*)((char*)d_ws + 262144);

  prep_weights<<<72, 256, 0, stream>>>(Wp, W1, W2, wpf, w1f, w2f);
  fused_kernel<<<NBLOCKS, 256, 0, stream>>>(x, b1, b2, wpf, w1f, w2f, out);
}